// Round 7
// baseline (496.954 us; speedup 1.0000x reference)
//
#include <hip/hip_runtime.h>
#include <stdint.h>

// SplitAttention: x->(x_tok|x_pos); Q=x_pos@Wq K=x_pos@Wk V=x_tok@Wv;
// causal 16-head attention (d=64); out = attn @ Wo. All MFMA bf16.
//
// R7: attn LDS tiles padded to 36-halfword rows (2-way banks, conflict-free
// per m136), staging writes swizzled to match, Osh aliased onto Ksh ->
// 18.4 KB LDS -> 8 blocks/CU; grid unpaired 2048 blocks. gemm_qkv V-epilogue
// stores u16x4 runs (perm is affine in k&3).

typedef unsigned short u16;
typedef __bf16 bf16;
typedef bf16 bf16x8 __attribute__((ext_vector_type(8)));
typedef u16 u16x8 __attribute__((ext_vector_type(8)));
typedef u16 u16x4 __attribute__((ext_vector_type(4)));
typedef float f32x4 __attribute__((ext_vector_type(4)));
typedef uint32_t u32x4 __attribute__((ext_vector_type(4)));

__device__ __forceinline__ u16 cvt_bf16(float f) {
  uint32_t u = __builtin_bit_cast(uint32_t, f);
  u += 0x7FFFu + ((u >> 16) & 1u);   // RNE
  return (u16)(u >> 16);
}

// pack two f32 -> (bf16 lo | bf16 hi) with +0.5ulp rounding, one v_perm_b32
__device__ __forceinline__ uint32_t pack2_bf16(float lo, float hi) {
  uint32_t a = __builtin_bit_cast(uint32_t, lo) + 0x8000u;
  uint32_t b = __builtin_bit_cast(uint32_t, hi) + 0x8000u;
  return __builtin_amdgcn_perm(b, a, 0x07060302u);
}

__device__ __forceinline__ f32x4 mfma_bf(bf16x8 a, bf16x8 b, f32x4 c) {
  return __builtin_amdgcn_mfma_f32_16x16x32_bf16(a, b, c, 0, 0, 0);
}

typedef __attribute__((address_space(1))) const uint32_t g_u32;
typedef __attribute__((address_space(3))) uint32_t l_u32;
__device__ __forceinline__ void gload16(const u16* g, u16* l) {
  __builtin_amdgcn_global_load_lds((g_u32*)g, (l_u32*)l, 16, 0, 0);
}

// ---------------- x -> bf16 tok/pos split
__global__ __launch_bounds__(256) void prep_x(
    const float* __restrict__ x, u16* __restrict__ xtok,
    u16* __restrict__ xpos) {
  int idx = blockIdx.x * 256 + threadIdx.x;
  int row = idx >> 8;
  int c4 = (idx & 255) * 4;
  float4 v = *(const float4*)(x + (size_t)row * 1024 + c4);
  u16x4 b = {cvt_bf16(v.x), cvt_bf16(v.y), cvt_bf16(v.z), cvt_bf16(v.w)};
  u16* dst = (c4 < 512) ? (xtok + (size_t)row * 512 + c4)
                        : (xpos + (size_t)row * 512 + c4 - 512);
  *(u16x4*)dst = b;
}

// ---------------- W[k][n] f32 -> Wt[n][k] bf16 (z=0..2: 512x1024; z=3: Wo 1024x1024)
__global__ __launch_bounds__(256) void prep_w(
    const float* __restrict__ Wq, const float* __restrict__ Wk,
    const float* __restrict__ Wv, const float* __restrict__ Wo,
    u16* __restrict__ Wt, u16* __restrict__ WoT) {
  const int z = blockIdx.z;
  const float* src = (z == 0) ? Wq : (z == 1) ? Wk : (z == 2) ? Wv : Wo;
  const int K = (z == 3) ? 1024 : 512;
  u16* dst = (z == 3) ? WoT : (Wt + (size_t)z * 1024 * 512);
  const int k0 = blockIdx.y * 64, n0 = blockIdx.x * 64;
  if (k0 >= K) return;
  __shared__ u16 T[64][68];
  const int tid = threadIdx.x;
  const int r = tid >> 4, c = (tid & 15) * 4;
#pragma unroll
  for (int i = 0; i < 4; i++) {
    float4 v = *(const float4*)(src + (size_t)(k0 + r + i * 16) * 1024 + n0 + c);
    u16x4 b = {cvt_bf16(v.x), cvt_bf16(v.y), cvt_bf16(v.z), cvt_bf16(v.w)};
    *(u16x4*)&T[r + i * 16][c] = b;
  }
  __syncthreads();
#pragma unroll
  for (int i = 0; i < 4; i++) {
    int n = r + i * 16;
    u16x4 v;
#pragma unroll
    for (int j = 0; j < 4; j++) v[j] = T[c + j][n];
    *(u16x4*)(dst + (size_t)(n0 + n) * K + k0 + c) = v;
  }
}

// ---------------- QKV projection (bf16 in, m97-style)
// z=0 (Q, pre-scaled), z=1 (K): write (b,h,t,d). z=2 (V): write permuted
// [bh][d][tpos] (fused vtrans), tpos = (t&~63)+(k&32)+((k>>4)&1)*4+((k>>2)&3)*8+(k&3)
// which is affine in (k&3) -> u16x4 runs along the 4 C-regs (consecutive t).
__global__ __launch_bounds__(256) void gemm_qkv(
    const u16* __restrict__ xtok, const u16* __restrict__ xpos,
    const u16* __restrict__ Wt, u16* __restrict__ qkv,
    u16* __restrict__ vperm) {
  const int z = blockIdx.z;
  const u16* A = (z == 2) ? xtok : xpos;
  const u16* Bt = Wt + (size_t)z * 1024 * 512;
  u16* outp = qkv + (size_t)z * (64u * 2048u * 64u);
  const float osc = (z == 0) ? 0.18033688011112042f : 1.0f;  // 0.125*log2e

  const int m0 = blockIdx.y * 128;
  const int n0 = blockIdx.x * 128;
  const int tid = threadIdx.x;
  const int lane = tid & 63;
  const int w = tid >> 6;
  const int wm = (w & 1) * 64;
  const int wn = (w >> 1) * 64;
  const int mrow = lane & 15;
  const int quad = lane >> 4;

  __shared__ __align__(16) u16 Ash[128 * 32];
  __shared__ __align__(16) u16 Bsh[128 * 32];

  f32x4 acc[4][4];
#pragma unroll
  for (int i = 0; i < 4; i++)
#pragma unroll
    for (int j = 0; j < 4; j++) acc[i][j] = (f32x4){0.f, 0.f, 0.f, 0.f};

  const int sr = w * 16 + (lane >> 2);
  const int sc = (lane & 3) * 8;
  const u16* gA = A + (size_t)(m0 + sr) * 512 + sc;
  const u16* gB = Bt + (size_t)(n0 + sr) * 512 + sc;
  u16* lA = Ash + sr * 32 + sc;
  u16* lB = Bsh + sr * 32 + sc;

  for (int kb = 0; kb < 512; kb += 32) {
    __syncthreads();
    gload16(gA + kb, lA);
    gload16(gA + 64 * 512 + kb, lA + 64 * 32);
    gload16(gB + kb, lB);
    gload16(gB + 64 * 512 + kb, lB + 64 * 32);
    __syncthreads();

    bf16x8 af[4], bfr[4];
#pragma unroll
    for (int mi = 0; mi < 4; mi++)
      af[mi] = *(const bf16x8*)(Ash + (wm + mi * 16 + mrow) * 32 + quad * 8);
#pragma unroll
    for (int ni = 0; ni < 4; ni++)
      bfr[ni] = *(const bf16x8*)(Bsh + (wn + ni * 16 + mrow) * 32 + quad * 8);
#pragma unroll
    for (int mi = 0; mi < 4; mi++)
#pragma unroll
      for (int ni = 0; ni < 4; ni++)
        acc[mi][ni] = mfma_bf(af[mi], bfr[ni], acc[mi][ni]);
  }

  if (z != 2) {
#pragma unroll
    for (int mi = 0; mi < 4; mi++)
#pragma unroll
      for (int ni = 0; ni < 4; ni++)
#pragma unroll
        for (int r = 0; r < 4; r++) {
          int m = m0 + wm + mi * 16 + quad * 4 + r;
          int n = n0 + wn + ni * 16 + mrow;
          int bb = m >> 11, t = m & 2047;
          int h = n >> 6, d = n & 63;
          outp[(((size_t)(bb * 16 + h)) * 2048 + t) * 64 + d] =
              cvt_bf16(acc[mi][ni][r] * osc);
        }
  } else {
#pragma unroll
    for (int mi = 0; mi < 4; mi++)
#pragma unroll
      for (int ni = 0; ni < 4; ni++) {
        int m = m0 + wm + mi * 16 + quad * 4;   // 4-aligned t base
        int n = n0 + wn + ni * 16 + mrow;
        int bb = m >> 11, t = m & 2047;
        int h = n >> 6, d = n & 63;
        int k6 = t & 63;
        int pos = (k6 & 32) + ((k6 >> 4) & 1) * 4 + ((k6 >> 2) & 3) * 8;
        u16x4 v = {cvt_bf16(acc[mi][ni][0]), cvt_bf16(acc[mi][ni][1]),
                   cvt_bf16(acc[mi][ni][2]), cvt_bf16(acc[mi][ni][3])};
        *(u16x4*)(vperm + (((size_t)(bb * 16 + h)) * 64 + d) * 2048 +
                  (t & ~63) + pos) = v;
      }
  }
}

// ---------------- Flash attention (S^T / O^T, no max, 64-row q-tiles)
// LDS rows padded to 36 halfwords (18 words) -> frag read banks (18m+4q)%32
// are 16 distinct bases per phase -> 2-way (free). Osh aliased onto Ksh.
// Grid: 64 bh x 32 q-tiles = 2048 blocks = 8/CU; round-robin dispatch
// balances the causal qt+1 iteration counts (120-144 iters/CU).
__global__ __launch_bounds__(256, 8) void attn(
    const u16* __restrict__ qkv, const u16* __restrict__ vperm,
    u16* __restrict__ aout) {
  const int bh = blockIdx.x;
  const int qt = blockIdx.y;   // 0..31
  const int bb = bh >> 4, h = bh & 15;
  const u16* Qp = qkv + (size_t)bh * (2048 * 64);
  const u16* Kp = qkv + (size_t)(64 + bh) * (2048 * 64);
  const u16* Vp = vperm + (size_t)bh * (64 * 2048);

  __shared__ __align__(16) u16 S[9216];   // 18432 B
  u16* Ksh0 = S;            // [64][36]
  u16* Ksh1 = S + 2304;
  u16* Vsh0 = S + 4608;
  u16* Vsh1 = S + 6912;
  u16* Osh  = S;            // epilogue alias, [4][16][72]

  const int tid = threadIdx.x;
  const int lane = tid & 63;
  const int w = tid >> 6;
  const int mrow = lane & 15;
  const int quad = lane >> 4;
  const int srow = w * 16 + (lane & 15);  // staging row 0..63
  const int sch = (lane >> 4) * 8;        // halfword chunk 0,8,16,24

  const u16x8 onesu = {0x3F80, 0x3F80, 0x3F80, 0x3F80,
                       0x3F80, 0x3F80, 0x3F80, 0x3F80};
  const bf16x8 ones = __builtin_bit_cast(bf16x8, onesu);

  const u16* kgb = Kp + (size_t)srow * 64 + sch;    // + k0*64 per tile
  const u16* vgb = Vp + (size_t)srow * 2048 + sch;  // + k0 per tile
  const int lidx = srow * 36 + sch;

  const int q0 = qt * 64;
  const int nk = qt + 1;

  const u16* qrow = Qp + (size_t)(q0 + w * 16 + mrow) * 64 + quad * 8;
  const bf16x8 qf0 = *(const bf16x8*)qrow;
  const bf16x8 qf1 = *(const bf16x8*)(qrow + 32);
  f32x4 o[4], ol;
#pragma unroll
  for (int dt = 0; dt < 4; ++dt) o[dt] = (f32x4){0.f, 0.f, 0.f, 0.f};
  ol = (f32x4){0.f, 0.f, 0.f, 0.f};

  // prefetch tile 0
  u16x8 ka0 = *(const u16x8*)kgb;
  u16x8 ka1 = *(const u16x8*)(kgb + 32);
  u16x8 va0 = *(const u16x8*)vgb;
  u16x8 va1 = *(const u16x8*)(vgb + 32);

  for (int it = 0; it < nk; ++it) {
    __syncthreads();   // prev iter's LDS readers done
    *(u16x8*)(Ksh0 + lidx) = ka0;
    *(u16x8*)(Ksh1 + lidx) = ka1;
    *(u16x8*)(Vsh0 + lidx) = va0;
    *(u16x8*)(Vsh1 + lidx) = va1;
    __syncthreads();   // LDS tile visible

    if (it + 1 < nk) {   // issue next tile's loads; land during compute
      const int kn = (it + 1) * 64;
      ka0 = *(const u16x8*)(kgb + (size_t)kn * 64);
      ka1 = *(const u16x8*)(kgb + (size_t)kn * 64 + 32);
      va0 = *(const u16x8*)(vgb + kn);
      va1 = *(const u16x8*)(vgb + kn + 32);
    }

    const int k0 = it * 64;
    // S^T = K · Q^T  (C: row = key-in-tile = quad*4+r, col = q = mrow)
    f32x4 s[4];
#pragma unroll
    for (int nt = 0; nt < 4; ++nt) {
      bf16x8 kf0 = *(const bf16x8*)(Ksh0 + (nt * 16 + mrow) * 36 + quad * 8);
      bf16x8 kf1 = *(const bf16x8*)(Ksh1 + (nt * 16 + mrow) * 36 + quad * 8);
      f32x4 zz = (f32x4){0.f, 0.f, 0.f, 0.f};
      zz = mfma_bf(kf0, qf0, zz);
      zz = mfma_bf(kf1, qf1, zz);
      s[nt] = zz;
    }

    if (it == nk - 1) {   // diagonal tile: causal mask
      const int q = q0 + w * 16 + mrow;
#pragma unroll
      for (int nt = 0; nt < 4; ++nt)
#pragma unroll
        for (int r = 0; r < 4; ++r)
          if (k0 + nt * 16 + quad * 4 + r > q) s[nt][r] = -1e30f;
    }
    // p = exp2(s), no max subtraction (|s| bounded << 127)
#pragma unroll
    for (int nt = 0; nt < 4; ++nt)
#pragma unroll
      for (int r = 0; r < 4; ++r)
        s[nt][r] = __builtin_amdgcn_exp2f(s[nt][r]);

    // P^T B-frags packed from s[] via v_perm
    u32x4 w0 = {pack2_bf16(s[0][0], s[0][1]), pack2_bf16(s[0][2], s[0][3]),
                pack2_bf16(s[1][0], s[1][1]), pack2_bf16(s[1][2], s[1][3])};
    u32x4 w1 = {pack2_bf16(s[2][0], s[2][1]), pack2_bf16(s[2][2], s[2][3]),
                pack2_bf16(s[3][0], s[3][1]), pack2_bf16(s[3][2], s[3][3])};
    bf16x8 pf0 = __builtin_bit_cast(bf16x8, w0);
    bf16x8 pf1 = __builtin_bit_cast(bf16x8, w1);

    // l row-sum via ones A-frag; O^T += V^T · P^T
    ol = mfma_bf(ones, pf0, ol);
    ol = mfma_bf(ones, pf1, ol);
#pragma unroll
    for (int dt = 0; dt < 4; ++dt) {
      bf16x8 vf0 = *(const bf16x8*)(Vsh0 + (dt * 16 + mrow) * 36 + quad * 8);
      bf16x8 vf1 = *(const bf16x8*)(Vsh1 + (dt * 16 + mrow) * 36 + quad * 8);
      o[dt] = mfma_bf(vf0, pf0, o[dt]);
      o[dt] = mfma_bf(vf1, pf1, o[dt]);
    }
  }

  __syncthreads();   // all frag reads done before aliasing Osh onto Ksh
  // epilogue: normalize, transpose O^T -> O through per-wave LDS, store
  const float inv = 1.f / ol[0];
#pragma unroll
  for (int dt = 0; dt < 4; ++dt)
#pragma unroll
    for (int r = 0; r < 4; ++r)
      Osh[(w * 16 + mrow) * 72 + dt * 16 + quad * 4 + r] =
          cvt_bf16(o[dt][r] * inv);
#pragma unroll
  for (int p = 0; p < 2; ++p) {
    int ql = (lane >> 3) + 8 * p;
    int ch = lane & 7;
    u16x8 v = *(const u16x8*)(Osh + (w * 16 + ql) * 72 + ch * 8);
    int t = q0 + w * 16 + ql;
    *(u16x8*)(aout + ((size_t)(bb * 2048 + t)) * 1024 + h * 64 + ch * 8) = v;
  }
}

// ---------------- Output projection: aout(bf16) @ WoT(bf16 [n][k]) -> f32
__global__ __launch_bounds__(256) void gemm_out(
    const u16* __restrict__ Am, const u16* __restrict__ WoT,
    float* __restrict__ out) {
  const int m0 = blockIdx.y * 128;
  const int n0 = blockIdx.x * 128;
  const int tid = threadIdx.x;
  const int lane = tid & 63;
  const int w = tid >> 6;
  const int wm = (w & 1) * 64;
  const int wn = (w >> 1) * 64;
  const int mrow = lane & 15;
  const int quad = lane >> 4;

  __shared__ __align__(16) u16 Ash[128 * 32];
  __shared__ __align__(16) u16 Bsh[128 * 32];

  f32x4 acc[4][4];
#pragma unroll
  for (int i = 0; i < 4; i++)
#pragma unroll
    for (int j = 0; j < 4; j++) acc[i][j] = (f32x4){0.f, 0.f, 0.f, 0.f};

  const int sr = w * 16 + (lane >> 2);
  const int sc = (lane & 3) * 8;
  const u16* gA = Am + (size_t)(m0 + sr) * 1024 + sc;
  const u16* gB = WoT + (size_t)(n0 + sr) * 1024 + sc;
  u16* lA = Ash + sr * 32 + sc;
  u16* lB = Bsh + sr * 32 + sc;

  for (int kb = 0; kb < 1024; kb += 32) {
    __syncthreads();
    gload16(gA + kb, lA);
    gload16(gA + 64 * 1024 + kb, lA + 64 * 32);
    gload16(gB + kb, lB);
    gload16(gB + 64 * 1024 + kb, lB + 64 * 32);
    __syncthreads();

    bf16x8 af[4], bfr[4];
#pragma unroll
    for (int mi = 0; mi < 4; mi++)
      af[mi] = *(const bf16x8*)(Ash + (wm + mi * 16 + mrow) * 32 + quad * 8);
#pragma unroll
    for (int ni = 0; ni < 4; ni++)
      bfr[ni] = *(const bf16x8*)(Bsh + (wn + ni * 16 + mrow) * 32 + quad * 8);
#pragma unroll
    for (int mi = 0; mi < 4; mi++)
#pragma unroll
      for (int ni = 0; ni < 4; ni++)
        acc[mi][ni] = mfma_bf(af[mi], bfr[ni], acc[mi][ni]);
  }

#pragma unroll
  for (int mi = 0; mi < 4; mi++)
#pragma unroll
    for (int ni = 0; ni < 4; ni++)
#pragma unroll
      for (int r = 0; r < 4; r++) {
        int m = m0 + wm + mi * 16 + quad * 4 + r;
        int n = n0 + wn + ni * 16 + mrow;
        out[(size_t)m * 1024 + n] = acc[mi][ni][r];
      }
}

extern "C" void kernel_launch(void* const* d_in, const int* in_sizes, int n_in,
                              void* d_out, int out_size, void* d_ws, size_t ws_size,
                              hipStream_t stream) {
  const float* x  = (const float*)d_in[0];
  const float* Wq = (const float*)d_in[1];
  const float* Wk = (const float*)d_in[2];
  const float* Wv = (const float*)d_in[3];
  const float* Wo = (const float*)d_in[4];

  u16* qkv   = (u16*)d_ws;
  u16* vperm = qkv + (size_t)3 * 64 * 2048 * 64;
  u16* aout  = vperm + (size_t)64 * 64 * 2048;
  u16* xtok  = aout + (size_t)8192 * 1024;
  u16* xpos  = xtok + (size_t)8192 * 512;
  u16* Wt    = xpos + (size_t)8192 * 512;
  u16* WoT   = Wt + (size_t)3 * 1024 * 512;
  float* out = (float*)d_out;

  prep_x<<<dim3(8192), dim3(256), 0, stream>>>(x, xtok, xpos);
  prep_w<<<dim3(16, 16, 4), dim3(256), 0, stream>>>(Wq, Wk, Wv, Wo, Wt, WoT);
  gemm_qkv<<<dim3(8, 64, 3), dim3(256), 0, stream>>>(xtok, xpos, Wt, qkv, vperm);
  attn<<<dim3(64, 32), dim3(256), 0, stream>>>(qkv, vperm, aout);
  gemm_out<<<dim3(8, 64), dim3(256), 0, stream>>>(aout, WoT, out);
}

// Round 8
// 485.373 us; speedup vs baseline: 1.0239x; 1.0239x over previous
//
#include <hip/hip_runtime.h>
#include <stdint.h>

// SplitAttention: x->(x_tok|x_pos); Q=x_pos@Wq K=x_pos@Wk V=x_tok@Wv;
// causal 16-head attention (d=64); out = attn @ Wo. All MFMA bf16.
//
// R8: R7's conflict-free padded LDS (rows of 36 halfwords) + Osh alias +
// 2048-block grid, but launch_bounds (256,6) -- (256,8)'s 64-VGPR cap
// caused catastrophic scratch spills (WRITE_SIZE 16->92 MB in R7).

typedef unsigned short u16;
typedef __bf16 bf16;
typedef bf16 bf16x8 __attribute__((ext_vector_type(8)));
typedef u16 u16x8 __attribute__((ext_vector_type(8)));
typedef u16 u16x4 __attribute__((ext_vector_type(4)));
typedef float f32x4 __attribute__((ext_vector_type(4)));
typedef uint32_t u32x4 __attribute__((ext_vector_type(4)));

__device__ __forceinline__ u16 cvt_bf16(float f) {
  uint32_t u = __builtin_bit_cast(uint32_t, f);
  u += 0x7FFFu + ((u >> 16) & 1u);   // RNE
  return (u16)(u >> 16);
}

// pack two f32 -> (bf16 lo | bf16 hi) with +0.5ulp rounding, one v_perm_b32
__device__ __forceinline__ uint32_t pack2_bf16(float lo, float hi) {
  uint32_t a = __builtin_bit_cast(uint32_t, lo) + 0x8000u;
  uint32_t b = __builtin_bit_cast(uint32_t, hi) + 0x8000u;
  return __builtin_amdgcn_perm(b, a, 0x07060302u);
}

__device__ __forceinline__ f32x4 mfma_bf(bf16x8 a, bf16x8 b, f32x4 c) {
  return __builtin_amdgcn_mfma_f32_16x16x32_bf16(a, b, c, 0, 0, 0);
}

typedef __attribute__((address_space(1))) const uint32_t g_u32;
typedef __attribute__((address_space(3))) uint32_t l_u32;
__device__ __forceinline__ void gload16(const u16* g, u16* l) {
  __builtin_amdgcn_global_load_lds((g_u32*)g, (l_u32*)l, 16, 0, 0);
}

// ---------------- x -> bf16 tok/pos split
__global__ __launch_bounds__(256) void prep_x(
    const float* __restrict__ x, u16* __restrict__ xtok,
    u16* __restrict__ xpos) {
  int idx = blockIdx.x * 256 + threadIdx.x;
  int row = idx >> 8;
  int c4 = (idx & 255) * 4;
  float4 v = *(const float4*)(x + (size_t)row * 1024 + c4);
  u16x4 b = {cvt_bf16(v.x), cvt_bf16(v.y), cvt_bf16(v.z), cvt_bf16(v.w)};
  u16* dst = (c4 < 512) ? (xtok + (size_t)row * 512 + c4)
                        : (xpos + (size_t)row * 512 + c4 - 512);
  *(u16x4*)dst = b;
}

// ---------------- W[k][n] f32 -> Wt[n][k] bf16 (z=0..2: 512x1024; z=3: Wo 1024x1024)
__global__ __launch_bounds__(256) void prep_w(
    const float* __restrict__ Wq, const float* __restrict__ Wk,
    const float* __restrict__ Wv, const float* __restrict__ Wo,
    u16* __restrict__ Wt, u16* __restrict__ WoT) {
  const int z = blockIdx.z;
  const float* src = (z == 0) ? Wq : (z == 1) ? Wk : (z == 2) ? Wv : Wo;
  const int K = (z == 3) ? 1024 : 512;
  u16* dst = (z == 3) ? WoT : (Wt + (size_t)z * 1024 * 512);
  const int k0 = blockIdx.y * 64, n0 = blockIdx.x * 64;
  if (k0 >= K) return;
  __shared__ u16 T[64][68];
  const int tid = threadIdx.x;
  const int r = tid >> 4, c = (tid & 15) * 4;
#pragma unroll
  for (int i = 0; i < 4; i++) {
    float4 v = *(const float4*)(src + (size_t)(k0 + r + i * 16) * 1024 + n0 + c);
    u16x4 b = {cvt_bf16(v.x), cvt_bf16(v.y), cvt_bf16(v.z), cvt_bf16(v.w)};
    *(u16x4*)&T[r + i * 16][c] = b;
  }
  __syncthreads();
#pragma unroll
  for (int i = 0; i < 4; i++) {
    int n = r + i * 16;
    u16x4 v;
#pragma unroll
    for (int j = 0; j < 4; j++) v[j] = T[c + j][n];
    *(u16x4*)(dst + (size_t)(n0 + n) * K + k0 + c) = v;
  }
}

// ---------------- QKV projection (bf16 in, m97-style)
// z=0 (Q, pre-scaled), z=1 (K): write (b,h,t,d). z=2 (V): write permuted
// [bh][d][tpos] (fused vtrans), tpos = (t&~63)+(k&32)+((k>>4)&1)*4+((k>>2)&3)*8+(k&3)
// which is affine in (k&3) -> u16x4 runs along the 4 C-regs (consecutive t).
__global__ __launch_bounds__(256) void gemm_qkv(
    const u16* __restrict__ xtok, const u16* __restrict__ xpos,
    const u16* __restrict__ Wt, u16* __restrict__ qkv,
    u16* __restrict__ vperm) {
  const int z = blockIdx.z;
  const u16* A = (z == 2) ? xtok : xpos;
  const u16* Bt = Wt + (size_t)z * 1024 * 512;
  u16* outp = qkv + (size_t)z * (64u * 2048u * 64u);
  const float osc = (z == 0) ? 0.18033688011112042f : 1.0f;  // 0.125*log2e

  const int m0 = blockIdx.y * 128;
  const int n0 = blockIdx.x * 128;
  const int tid = threadIdx.x;
  const int lane = tid & 63;
  const int w = tid >> 6;
  const int wm = (w & 1) * 64;
  const int wn = (w >> 1) * 64;
  const int mrow = lane & 15;
  const int quad = lane >> 4;

  __shared__ __align__(16) u16 Ash[128 * 32];
  __shared__ __align__(16) u16 Bsh[128 * 32];

  f32x4 acc[4][4];
#pragma unroll
  for (int i = 0; i < 4; i++)
#pragma unroll
    for (int j = 0; j < 4; j++) acc[i][j] = (f32x4){0.f, 0.f, 0.f, 0.f};

  const int sr = w * 16 + (lane >> 2);
  const int sc = (lane & 3) * 8;
  const u16* gA = A + (size_t)(m0 + sr) * 512 + sc;
  const u16* gB = Bt + (size_t)(n0 + sr) * 512 + sc;
  u16* lA = Ash + sr * 32 + sc;
  u16* lB = Bsh + sr * 32 + sc;

  for (int kb = 0; kb < 512; kb += 32) {
    __syncthreads();
    gload16(gA + kb, lA);
    gload16(gA + 64 * 512 + kb, lA + 64 * 32);
    gload16(gB + kb, lB);
    gload16(gB + 64 * 512 + kb, lB + 64 * 32);
    __syncthreads();

    bf16x8 af[4], bfr[4];
#pragma unroll
    for (int mi = 0; mi < 4; mi++)
      af[mi] = *(const bf16x8*)(Ash + (wm + mi * 16 + mrow) * 32 + quad * 8);
#pragma unroll
    for (int ni = 0; ni < 4; ni++)
      bfr[ni] = *(const bf16x8*)(Bsh + (wn + ni * 16 + mrow) * 32 + quad * 8);
#pragma unroll
    for (int mi = 0; mi < 4; mi++)
#pragma unroll
      for (int ni = 0; ni < 4; ni++)
        acc[mi][ni] = mfma_bf(af[mi], bfr[ni], acc[mi][ni]);
  }

  if (z != 2) {
#pragma unroll
    for (int mi = 0; mi < 4; mi++)
#pragma unroll
      for (int ni = 0; ni < 4; ni++)
#pragma unroll
        for (int r = 0; r < 4; r++) {
          int m = m0 + wm + mi * 16 + quad * 4 + r;
          int n = n0 + wn + ni * 16 + mrow;
          int bb = m >> 11, t = m & 2047;
          int h = n >> 6, d = n & 63;
          outp[(((size_t)(bb * 16 + h)) * 2048 + t) * 64 + d] =
              cvt_bf16(acc[mi][ni][r] * osc);
        }
  } else {
#pragma unroll
    for (int mi = 0; mi < 4; mi++)
#pragma unroll
      for (int ni = 0; ni < 4; ni++) {
        int m = m0 + wm + mi * 16 + quad * 4;   // 4-aligned t base
        int n = n0 + wn + ni * 16 + mrow;
        int bb = m >> 11, t = m & 2047;
        int h = n >> 6, d = n & 63;
        int k6 = t & 63;
        int pos = (k6 & 32) + ((k6 >> 4) & 1) * 4 + ((k6 >> 2) & 3) * 8;
        u16x4 v = {cvt_bf16(acc[mi][ni][0]), cvt_bf16(acc[mi][ni][1]),
                   cvt_bf16(acc[mi][ni][2]), cvt_bf16(acc[mi][ni][3])};
        *(u16x4*)(vperm + (((size_t)(bb * 16 + h)) * 64 + d) * 2048 +
                  (t & ~63) + pos) = v;
      }
  }
}

// ---------------- Flash attention (S^T / O^T, no max, 64-row q-tiles)
// LDS rows padded to 36 halfwords -> frag-read banks 2-way only (free).
// Osh aliased onto Ksh. Grid 64 x 32 = 2048 blocks; launch_bounds (256,6)
// (NOT 8: 64-VGPR cap spills to scratch, R7).
__global__ __launch_bounds__(256, 6) void attn(
    const u16* __restrict__ qkv, const u16* __restrict__ vperm,
    u16* __restrict__ aout) {
  const int bh = blockIdx.x;
  const int qt = blockIdx.y;   // 0..31
  const int bb = bh >> 4, h = bh & 15;
  const u16* Qp = qkv + (size_t)bh * (2048 * 64);
  const u16* Kp = qkv + (size_t)(64 + bh) * (2048 * 64);
  const u16* Vp = vperm + (size_t)bh * (64 * 2048);

  __shared__ __align__(16) u16 S[9216];   // 18432 B
  u16* Ksh0 = S;            // [64][36]
  u16* Ksh1 = S + 2304;
  u16* Vsh0 = S + 4608;
  u16* Vsh1 = S + 6912;
  u16* Osh  = S;            // epilogue alias, [4][16][72]

  const int tid = threadIdx.x;
  const int lane = tid & 63;
  const int w = tid >> 6;
  const int mrow = lane & 15;
  const int quad = lane >> 4;
  const int srow = w * 16 + (lane & 15);  // staging row 0..63
  const int sch = (lane >> 4) * 8;        // halfword chunk 0,8,16,24

  const u16x8 onesu = {0x3F80, 0x3F80, 0x3F80, 0x3F80,
                       0x3F80, 0x3F80, 0x3F80, 0x3F80};
  const bf16x8 ones = __builtin_bit_cast(bf16x8, onesu);

  const u16* kgb = Kp + (size_t)srow * 64 + sch;    // + k0*64 per tile
  const u16* vgb = Vp + (size_t)srow * 2048 + sch;  // + k0 per tile
  const int lidx = srow * 36 + sch;

  const int q0 = qt * 64;
  const int nk = qt + 1;

  const u16* qrow = Qp + (size_t)(q0 + w * 16 + mrow) * 64 + quad * 8;
  const bf16x8 qf0 = *(const bf16x8*)qrow;
  const bf16x8 qf1 = *(const bf16x8*)(qrow + 32);
  f32x4 o[4], ol;
#pragma unroll
  for (int dt = 0; dt < 4; ++dt) o[dt] = (f32x4){0.f, 0.f, 0.f, 0.f};
  ol = (f32x4){0.f, 0.f, 0.f, 0.f};

  // prefetch tile 0
  u16x8 ka0 = *(const u16x8*)kgb;
  u16x8 ka1 = *(const u16x8*)(kgb + 32);
  u16x8 va0 = *(const u16x8*)vgb;
  u16x8 va1 = *(const u16x8*)(vgb + 32);

  for (int it = 0; it < nk; ++it) {
    __syncthreads();   // prev iter's LDS readers done
    *(u16x8*)(Ksh0 + lidx) = ka0;
    *(u16x8*)(Ksh1 + lidx) = ka1;
    *(u16x8*)(Vsh0 + lidx) = va0;
    *(u16x8*)(Vsh1 + lidx) = va1;
    __syncthreads();   // LDS tile visible

    if (it + 1 < nk) {   // issue next tile's loads; land during compute
      const int kn = (it + 1) * 64;
      ka0 = *(const u16x8*)(kgb + (size_t)kn * 64);
      ka1 = *(const u16x8*)(kgb + (size_t)kn * 64 + 32);
      va0 = *(const u16x8*)(vgb + kn);
      va1 = *(const u16x8*)(vgb + kn + 32);
    }

    const int k0 = it * 64;
    // S^T = K · Q^T  (C: row = key-in-tile = quad*4+r, col = q = mrow)
    f32x4 s[4];
#pragma unroll
    for (int nt = 0; nt < 4; ++nt) {
      bf16x8 kf0 = *(const bf16x8*)(Ksh0 + (nt * 16 + mrow) * 36 + quad * 8);
      bf16x8 kf1 = *(const bf16x8*)(Ksh1 + (nt * 16 + mrow) * 36 + quad * 8);
      f32x4 zz = (f32x4){0.f, 0.f, 0.f, 0.f};
      zz = mfma_bf(kf0, qf0, zz);
      zz = mfma_bf(kf1, qf1, zz);
      s[nt] = zz;
    }

    if (it == nk - 1) {   // diagonal tile: causal mask
      const int q = q0 + w * 16 + mrow;
#pragma unroll
      for (int nt = 0; nt < 4; ++nt)
#pragma unroll
        for (int r = 0; r < 4; ++r)
          if (k0 + nt * 16 + quad * 4 + r > q) s[nt][r] = -1e30f;
    }
    // p = exp2(s), no max subtraction (|s| bounded << 127)
#pragma unroll
    for (int nt = 0; nt < 4; ++nt)
#pragma unroll
      for (int r = 0; r < 4; ++r)
        s[nt][r] = __builtin_amdgcn_exp2f(s[nt][r]);

    // P^T B-frags packed from s[] via v_perm
    u32x4 w0 = {pack2_bf16(s[0][0], s[0][1]), pack2_bf16(s[0][2], s[0][3]),
                pack2_bf16(s[1][0], s[1][1]), pack2_bf16(s[1][2], s[1][3])};
    u32x4 w1 = {pack2_bf16(s[2][0], s[2][1]), pack2_bf16(s[2][2], s[2][3]),
                pack2_bf16(s[3][0], s[3][1]), pack2_bf16(s[3][2], s[3][3])};
    bf16x8 pf0 = __builtin_bit_cast(bf16x8, w0);
    bf16x8 pf1 = __builtin_bit_cast(bf16x8, w1);

    // l row-sum via ones A-frag; O^T += V^T · P^T
    ol = mfma_bf(ones, pf0, ol);
    ol = mfma_bf(ones, pf1, ol);
#pragma unroll
    for (int dt = 0; dt < 4; ++dt) {
      bf16x8 vf0 = *(const bf16x8*)(Vsh0 + (dt * 16 + mrow) * 36 + quad * 8);
      bf16x8 vf1 = *(const bf16x8*)(Vsh1 + (dt * 16 + mrow) * 36 + quad * 8);
      o[dt] = mfma_bf(vf0, pf0, o[dt]);
      o[dt] = mfma_bf(vf1, pf1, o[dt]);
    }
  }

  __syncthreads();   // all frag reads done before aliasing Osh onto Ksh
  // epilogue: normalize, transpose O^T -> O through per-wave LDS, store
  const float inv = 1.f / ol[0];
#pragma unroll
  for (int dt = 0; dt < 4; ++dt)
#pragma unroll
    for (int r = 0; r < 4; ++r)
      Osh[(w * 16 + mrow) * 72 + dt * 16 + quad * 4 + r] =
          cvt_bf16(o[dt][r] * inv);
#pragma unroll
  for (int p = 0; p < 2; ++p) {
    int ql = (lane >> 3) + 8 * p;
    int ch = lane & 7;
    u16x8 v = *(const u16x8*)(Osh + (w * 16 + ql) * 72 + ch * 8);
    int t = q0 + w * 16 + ql;
    *(u16x8*)(aout + ((size_t)(bb * 2048 + t)) * 1024 + h * 64 + ch * 8) = v;
  }
}

// ---------------- Output projection: aout(bf16) @ WoT(bf16 [n][k]) -> f32
__global__ __launch_bounds__(256) void gemm_out(
    const u16* __restrict__ Am, const u16* __restrict__ WoT,
    float* __restrict__ out) {
  const int m0 = blockIdx.y * 128;
  const int n0 = blockIdx.x * 128;
  const int tid = threadIdx.x;
  const int lane = tid & 63;
  const int w = tid >> 6;
  const int wm = (w & 1) * 64;
  const int wn = (w >> 1) * 64;
  const int mrow = lane & 15;
  const int quad = lane >> 4;

  __shared__ __align__(16) u16 Ash[128 * 32];
  __shared__ __align__(16) u16 Bsh[128 * 32];

  f32x4 acc[4][4];
#pragma unroll
  for (int i = 0; i < 4; i++)
#pragma unroll
    for (int j = 0; j < 4; j++) acc[i][j] = (f32x4){0.f, 0.f, 0.f, 0.f};

  const int sr = w * 16 + (lane >> 2);
  const int sc = (lane & 3) * 8;
  const u16* gA = Am + (size_t)(m0 + sr) * 1024 + sc;
  const u16* gB = WoT + (size_t)(n0 + sr) * 1024 + sc;
  u16* lA = Ash + sr * 32 + sc;
  u16* lB = Bsh + sr * 32 + sc;

  for (int kb = 0; kb < 1024; kb += 32) {
    __syncthreads();
    gload16(gA + kb, lA);
    gload16(gA + 64 * 1024 + kb, lA + 64 * 32);
    gload16(gB + kb, lB);
    gload16(gB + 64 * 1024 + kb, lB + 64 * 32);
    __syncthreads();

    bf16x8 af[4], bfr[4];
#pragma unroll
    for (int mi = 0; mi < 4; mi++)
      af[mi] = *(const bf16x8*)(Ash + (wm + mi * 16 + mrow) * 32 + quad * 8);
#pragma unroll
    for (int ni = 0; ni < 4; ni++)
      bfr[ni] = *(const bf16x8*)(Bsh + (wn + ni * 16 + mrow) * 32 + quad * 8);
#pragma unroll
    for (int mi = 0; mi < 4; mi++)
#pragma unroll
      for (int ni = 0; ni < 4; ni++)
        acc[mi][ni] = mfma_bf(af[mi], bfr[ni], acc[mi][ni]);
  }

#pragma unroll
  for (int mi = 0; mi < 4; mi++)
#pragma unroll
    for (int ni = 0; ni < 4; ni++)
#pragma unroll
      for (int r = 0; r < 4; r++) {
        int m = m0 + wm + mi * 16 + quad * 4 + r;
        int n = n0 + wn + ni * 16 + mrow;
        out[(size_t)m * 1024 + n] = acc[mi][ni][r];
      }
}

extern "C" void kernel_launch(void* const* d_in, const int* in_sizes, int n_in,
                              void* d_out, int out_size, void* d_ws, size_t ws_size,
                              hipStream_t stream) {
  const float* x  = (const float*)d_in[0];
  const float* Wq = (const float*)d_in[1];
  const float* Wk = (const float*)d_in[2];
  const float* Wv = (const float*)d_in[3];
  const float* Wo = (const float*)d_in[4];

  u16* qkv   = (u16*)d_ws;
  u16* vperm = qkv + (size_t)3 * 64 * 2048 * 64;
  u16* aout  = vperm + (size_t)64 * 64 * 2048;
  u16* xtok  = aout + (size_t)8192 * 1024;
  u16* xpos  = xtok + (size_t)8192 * 512;
  u16* Wt    = xpos + (size_t)8192 * 512;
  u16* WoT   = Wt + (size_t)3 * 1024 * 512;
  float* out = (float*)d_out;

  prep_x<<<dim3(8192), dim3(256), 0, stream>>>(x, xtok, xpos);
  prep_w<<<dim3(16, 16, 4), dim3(256), 0, stream>>>(Wq, Wk, Wv, Wo, Wt, WoT);
  gemm_qkv<<<dim3(8, 64, 3), dim3(256), 0, stream>>>(xtok, xpos, Wt, qkv, vperm);
  attn<<<dim3(64, 32), dim3(256), 0, stream>>>(qkv, vperm, aout);
  gemm_out<<<dim3(8, 64), dim3(256), 0, stream>>>(aout, WoT, out);
}